// Round 8
// baseline (3053.163 us; speedup 1.0000x reference)
//
#include <hip/hip_runtime.h>
#include <hip/hip_bf16.h>

// TSGCN: GCN(2 layers, fused) -> GRU(4096->256) -> GRU(256->256) -> FC head
// B=32 S=512 N=64 F=16 G=64 H=256.
// R8: (1) GEMM XCD-locality swizzle (6 same-A blocks colocate on one XCD's
// L2, killing the 6x A re-stream from HBM); (2) GRU holds ALL 48 weight
// fragments in AGPRs (no per-step weight LDS reads) + gi prefetched one
// step ahead. GRU h state fp32; MFMA operands f16.

#define EPS_BN 1e-5f

typedef float f32x4 __attribute__((ext_vector_type(4)));
typedef unsigned u32x4v __attribute__((ext_vector_type(4)));

// ---------------------------------------------------- fp32 -> f16 hi/lo split
__global__ void k_split16(const float* __restrict__ src,
                          _Float16* __restrict__ hi, _Float16* __restrict__ lo,
                          int n) {
  int i = blockIdx.x * 256 + threadIdx.x;
  if (i >= n) return;
  float v = src[i];
  _Float16 h = (_Float16)v;
  hi[i] = h;
  lo[i] = (_Float16)(v - (float)h);
}

// ---------------------------------------------- pack Whh into MFMA B-fragments
// Tile map: fragment (w, nt, ks) covers n-tile (w + 8*nt):
//   n = 16*w + 128*nt + (l&15), k = 32*ks + 8*(l>>4) + j.
__global__ void k_pack_frag(const float* __restrict__ whh, uint4* __restrict__ wp) {
  int tid = blockIdx.x * 256 + threadIdx.x;
  if (tid >= 24576) return;
  int l = tid & 63;
  int rest = tid >> 6;
  int ks = rest & 7; rest >>= 3;
  int nt = rest % 6;
  int w  = rest / 6;
  int n  = 16 * w + 128 * nt + (l & 15);
  int kb = ks * 32 + (l >> 4) * 8;
  const float* src = whh + (size_t)n * 256 + kb;
  unsigned dw[4];
#pragma unroll
  for (int d = 0; d < 4; ++d) {
    unsigned short lo = __builtin_bit_cast(unsigned short, (_Float16)src[2 * d]);
    unsigned short hi = __builtin_bit_cast(unsigned short, (_Float16)src[2 * d + 1]);
    dw[d] = (unsigned)lo | ((unsigned)hi << 16);
  }
  wp[tid] = make_uint4(dw[0], dw[1], dw[2], dw[3]);
}

// ------------------------------------------------------------- fused GCN
__global__ __launch_bounds__(256) void k_gcn(
    const float* __restrict__ x, const float* __restrict__ adj,
    const float* __restrict__ W0, const float* __restrict__ b0,
    const float* __restrict__ W1, const float* __restrict__ b1,
    const float* __restrict__ bn_g, const float* __restrict__ bn_b,
    const float* __restrict__ bn_m, const float* __restrict__ bn_v,
    _Float16* __restrict__ seqh, _Float16* __restrict__ seql, int base)
{
  __shared__ float As[4096];
  __shared__ float Xs[1024];
  __shared__ float Hs[4096];
  __shared__ float Qs[4096];
  __shared__ float bnm_s[64], bns_s[64], bnb_s[64];

  const int t = threadIdx.x;
  const int lane = t & 63;
  const int w = t >> 6;
  const int m = base + blockIdx.x;

  {
    const float4* a4 = (const float4*)adj;
    float4* s4 = (float4*)As;
#pragma unroll
    for (int p = 0; p < 4; ++p) s4[t + 256 * p] = a4[t + 256 * p];
    ((float4*)Xs)[t] = ((const float4*)(x + (size_t)m * 1024))[t];
  }
  if (t < 64) {
    bns_s[t] = rsqrtf(bn_v[t] + EPS_BN) * bn_g[t];
    bnm_s[t] = bn_m[t];
    bnb_s[t] = bn_b[t];
  }
  float w0r[16];
#pragma unroll
  for (int f = 0; f < 16; ++f) w0r[f] = W0[f * 64 + lane];
  const float b0v = b0[lane], b1v = b1[lane];
  __syncthreads();

  float p[64];
#pragma unroll
  for (int v = 0; v < 64; ++v) {
    float acc = 0.f;
#pragma unroll
    for (int f = 0; f < 16; ++f) acc += Xs[v * 16 + f] * w0r[f];
    p[v] = acc;
  }
#pragma unroll
  for (int uu = 0; uu < 16; ++uu) {
    int u = w * 16 + uu;
    float acc = 0.f;
#pragma unroll
    for (int v = 0; v < 64; ++v) acc += As[u * 64 + v] * p[v];
    float h1 = fmaxf(acc + b0v, 0.f);
    h1 = (h1 - bnm_s[u]) * bns_s[u] + bnb_s[u];
    Hs[u * 64 + lane] = h1;
  }
  __syncthreads();
  float w1r[64];
#pragma unroll
  for (int f = 0; f < 64; ++f) w1r[f] = W1[f * 64 + lane];
#pragma unroll
  for (int vv = 0; vv < 16; ++vv) {
    int v = w * 16 + vv;
    float acc = 0.f;
#pragma unroll
    for (int f = 0; f < 64; ++f) acc += Hs[v * 64 + f] * w1r[f];
    Qs[v * 64 + lane] = acc;
  }
  __syncthreads();
  float q[64];
#pragma unroll
  for (int v = 0; v < 64; ++v) q[v] = Qs[v * 64 + lane];
  _Float16* oh = seqh + (size_t)blockIdx.x * 4096;
  _Float16* ol = seql + (size_t)blockIdx.x * 4096;
#pragma unroll
  for (int uu = 0; uu < 16; ++uu) {
    int u = w * 16 + uu;
    float acc = 0.f;
#pragma unroll
    for (int v = 0; v < 64; ++v) acc += As[u * 64 + v] * q[v];
    float val = fmaxf(acc + b1v, 0.f);
    _Float16 hv = (_Float16)val;
    oh[u * 64 + lane] = hv;
    ol[u * 64 + lane] = (_Float16)(val - (float)hv);
  }
}

// ----------------------------------------------- MFMA GEMM  C = A@B^T + bias
// 3-term hi/lo split, LDS-free, XCD-locality swizzled: XCD x processes works
// [x*T/8,(x+1)*T/8) ordered nb-fastest, so the 6 consumers of each A-tile
// run k-synchronized on one XCD and hit its L2 (A read ~once from HBM).
#define MFMA_VV(c, a, b) asm volatile("v_mfma_f32_16x16x32_f16 %0, %1, %2, %0" \
                                      : "+v"(c) : "v"(a), "v"(b))

__global__ __launch_bounds__(256, 2) void k_gemm_mfma(
    const _Float16* __restrict__ Ah, const _Float16* __restrict__ Al,
    const _Float16* __restrict__ Bh, const _Float16* __restrict__ Bl,
    const float* __restrict__ bias,
    float* __restrict__ C,
    int K, int mBlocks)
{
  const int T = gridDim.x;
  int work = blockIdx.x;
  if ((T & 7) == 0) {                 // bijective XCD-chunk remap
    const int chunk = T >> 3;
    work = (work & 7) * chunk + (work >> 3);
  }
  const int mb = work / 6;
  const int nb = work % 6;
  const int t = threadIdx.x;
  const int w = t >> 6, l = t & 63;
  const int m0 = mb * 128 + (w >> 1) * 64;
  const int n0 = nb * 128 + (w & 1) * 64;
  const int row = l & 15;
  const int kk = (l >> 4) * 8;

  const _Float16* ah = Ah + (size_t)(m0 + row) * K + kk;
  const _Float16* al = Al + (size_t)(m0 + row) * K + kk;
  const _Float16* bh = Bh + (size_t)(n0 + row) * K + kk;
  const _Float16* bl = Bl + (size_t)(n0 + row) * K + kk;

  f32x4 acc[4][4] = {};

  for (int kt = 0; kt < K; kt += 32) {
    u32x4v af_h[4], af_l[4], bf_h[4], bf_l[4];
#pragma unroll
    for (int i = 0; i < 4; ++i) {
      const size_t o = (size_t)(16 * i) * K + kt;
      af_h[i] = *(const u32x4v*)(ah + o);
      af_l[i] = *(const u32x4v*)(al + o);
      bf_h[i] = *(const u32x4v*)(bh + o);
      bf_l[i] = *(const u32x4v*)(bl + o);
    }
#pragma unroll
    for (int mi = 0; mi < 4; ++mi)
#pragma unroll
      for (int ni = 0; ni < 4; ++ni) {
        MFMA_VV(acc[mi][ni], af_h[mi], bf_h[ni]);
        MFMA_VV(acc[mi][ni], af_l[mi], bf_h[ni]);
        MFMA_VV(acc[mi][ni], af_h[mi], bf_l[ni]);
      }
  }

  asm volatile("s_nop 7\n\ts_nop 7");

  const int r4 = (l >> 4) * 4;
#pragma unroll
  for (int ni = 0; ni < 4; ++ni) {
    const float bv = bias[n0 + 16 * ni + row];
#pragma unroll
    for (int mi = 0; mi < 4; ++mi) {
      float* cp = C + (size_t)(m0 + 16 * mi + r4) * 768 + n0 + 16 * ni + row;
      cp[0]    = acc[mi][ni].x + bv;
      cp[768]  = acc[mi][ni].y + bv;
      cp[1536] = acc[mi][ni].z + bv;
      cp[2304] = acc[mi][ni].w + bv;
    }
  }
}

// ------------------------------------------------------------------ GRU layer
// R8: all 48 B-fragments AGPR-pinned (zero weight LDS traffic per step);
// gi prefetched one step ahead; wave-local gates; one barrier/step.
#define MFMA_A(c, a, b) asm volatile("v_mfma_f32_16x16x32_f16 %0, %1, %2, %0" \
                                     : "+v"(c) : "v"(a), "a"(b))

template <bool WF32, bool WF16>
__global__ __launch_bounds__(512, 2) void k_gru(
    const float* __restrict__ gi,        // [32*512][768]
    const uint4* __restrict__ wp,        // packed B-fragments (k_pack_frag)
    const float* __restrict__ bhh,       // [768]
    float* __restrict__ ys,              // [32*512][256] fp32   (if WF32)
    _Float16* __restrict__ ysh,          // [32*512][256] f16 hi (if WF16)
    _Float16* __restrict__ ysl)          // [32*512][256] f16 lo (if WF16)
{
  const int b = blockIdx.x;
  const int t = threadIdx.x;
  const int w = t >> 6;        // wave 0..7
  const int l = t & 63;

  __shared__ __align__(16) _Float16 h2[2][256];  // double-buffered f16 h

  const u32x4v* wp4 = (const u32x4v*)wp;
  const int wbase = w * 6;

  // ---- ALL B-fragments (8 k-slices x 6 tiles) -> named vars pinned via "a"
#define LBK(nt, ks) const u32x4v b##nt##_##ks = wp4[(((wbase + nt) * 8 + ks) << 6) + l];
#define LBNT(nt) LBK(nt,0) LBK(nt,1) LBK(nt,2) LBK(nt,3) \
                 LBK(nt,4) LBK(nt,5) LBK(nt,6) LBK(nt,7)
  LBNT(0) LBNT(1) LBNT(2) LBNT(3) LBNT(4) LBNT(5)
#undef LBNT
#undef LBK

  // lane's output index: l<32 active, j = 16w + (l&15) + 128*(l>>4)
  const int half = (l >> 4) & 1;
  const int j = 16 * w + (l & 15) + 128 * half;
  const bool act = (l < 32);
  float br = 0.f, bz = 0.f, bn = 0.f;
  float hold = 0.f;
  if (act) { br = bhh[j]; bz = bhh[256 + j]; bn = bhh[512 + j]; }
  if (t < 256) { h2[0][t] = (_Float16)0.f; h2[1][t] = (_Float16)0.f; }
  __syncthreads();

  const float* gib = gi + (size_t)b * 512 * 768;
  const char* h2c = (const char*)h2;
  const int g16 = (l >> 4) * 16;
  int cur = 0;

  // prefetch gi for step 0
  float ir = 0.f, iz = 0.f, inn = 0.f;
  if (act) { ir = gib[j]; iz = gib[256 + j]; inn = gib[512 + j]; }

#pragma unroll 1
  for (int step = 0; step < 512; ++step) {
    // issue next-step gi loads (hide HBM latency under the MFMA phase)
    float nir = 0.f, niz = 0.f, ninn = 0.f;
    if (act) {
      const int sn = step < 511 ? step + 1 : 511;
      const float* g = gib + (size_t)sn * 768;
      nir = g[j]; niz = g[256 + j]; ninn = g[512 + j];
    }

    f32x4 c0 = {0.f,0.f,0.f,0.f}, c1 = c0, c2 = c0, c3 = c0, c4 = c0, c5 = c0;

#define DOT_KS(ks) { \
    const u32x4v a = *(const u32x4v*)(h2c + cur * 512 + (ks) * 64 + g16); \
    MFMA_A(c0, a, b0_##ks); MFMA_A(c1, a, b1_##ks); MFMA_A(c2, a, b2_##ks); \
    MFMA_A(c3, a, b3_##ks); MFMA_A(c4, a, b4_##ks); MFMA_A(c5, a, b5_##ks); }
    DOT_KS(0) DOT_KS(1) DOT_KS(2) DOT_KS(3)
    DOT_KS(4) DOT_KS(5) DOT_KS(6) DOT_KS(7)
#undef DOT_KS
    // MFMA-write -> VALU-read hazard guard
    asm volatile("s_nop 7\n\ts_nop 7");

    // wave-local gate math: half 0 uses c0/c2/c4, half 1 uses c1/c3/c5
    if (act) {
      const float cr = half ? c1.x : c0.x;
      const float cz = half ? c3.x : c2.x;
      const float cn = half ? c5.x : c4.x;
      const float r = __builtin_amdgcn_rcpf(1.f + __expf(-(ir + cr + br)));
      const float z = __builtin_amdgcn_rcpf(1.f + __expf(-(iz + cz + bz)));
      const float e2 = __expf(2.f * (inn + r * (cn + bn)));
      const float n = 1.f - 2.f * __builtin_amdgcn_rcpf(e2 + 1.f);
      hold = (1.f - z) * n + z * hold;
      h2[cur ^ 1][j] = (_Float16)hold;
      const size_t rowi = (size_t)b * 512 + step;
      if (WF32) ys[rowi * 256 + j] = hold;
      if (WF16) {
        const _Float16 hh = (_Float16)hold;
        ysh[rowi * 256 + j] = hh;
        ysl[rowi * 256 + j] = (_Float16)(hold - (float)hh);
      }
    }
    __syncthreads();
    cur ^= 1;
    ir = nir; iz = niz; inn = ninn;
  }
}

// ------------------------------------------------------------------ FC head
__global__ __launch_bounds__(128) void k_head(
    const float* __restrict__ ys1,
    const float* __restrict__ fc1w, const float* __restrict__ fc1b,
    const float* __restrict__ fc2w, const float* __restrict__ fc2b,
    float* __restrict__ out)
{
  __shared__ float last[256];
  __shared__ float o1[128];
  const int b = blockIdx.x, t = threadIdx.x;
  const float* src = ys1 + (size_t)(b * 512 + 511) * 256;
  last[t] = src[t];
  last[128 + t] = src[128 + t];
  __syncthreads();
  float acc = fc1b[t];
#pragma unroll 8
  for (int k = 0; k < 256; ++k) acc += last[k] * fc1w[k * 128 + t];
  o1[t] = fmaxf(acc, 0.f);
  __syncthreads();
  if (t < 64) {
    float acc2 = fc2b[t];
#pragma unroll 8
    for (int i = 0; i < 128; ++i) acc2 += o1[i] * fc2w[i * 64 + t];
    out[b * 64 + t] = acc2;
  }
}

// ------------------------------------------------------------------ launcher
extern "C" void kernel_launch(void* const* d_in, const int* in_sizes, int n_in,
                              void* d_out, int out_size, void* d_ws, size_t ws_size,
                              hipStream_t stream)
{
  const float* x    = (const float*)d_in[0];
  const float* adj  = (const float*)d_in[1];
  const float* W0   = (const float*)d_in[2];
  const float* b0   = (const float*)d_in[3];
  const float* W1   = (const float*)d_in[4];
  const float* b1   = (const float*)d_in[5];
  const float* bng  = (const float*)d_in[6];
  const float* bnbb = (const float*)d_in[7];
  const float* bnm  = (const float*)d_in[8];
  const float* bnv  = (const float*)d_in[9];
  const float* Wih0 = (const float*)d_in[10];
  const float* Whh0 = (const float*)d_in[11];
  const float* bih0 = (const float*)d_in[12];
  const float* bhh0 = (const float*)d_in[13];
  const float* Wih1 = (const float*)d_in[14];
  const float* Whh1 = (const float*)d_in[15];
  const float* bih1 = (const float*)d_in[16];
  const float* bhh1 = (const float*)d_in[17];
  const float* fc1w = (const float*)d_in[18];
  const float* fc1b = (const float*)d_in[19];
  const float* fc2w = (const float*)d_in[20];
  const float* fc2b = (const float*)d_in[21];
  float* out = (float*)d_out;

  float* ws = (float*)d_ws;
  const size_t fixed = (size_t)16384 * 768 + (size_t)16384 * 256
                     + 2 * ((size_t)16384 * 128)
                     + 2 * 98304
                     + 2 * ((size_t)768 * 4096 / 2)
                     + 2 * ((size_t)768 * 256 / 2);
  int CHUNK = 16384;
  while (CHUNK > 128 && ((size_t)CHUNK * 4096 + fixed) * 4 > ws_size) CHUNK >>= 1;

  size_t off = 0;
  _Float16* seqh = (_Float16*)(ws + off); off += (size_t)CHUNK * 2048;
  _Float16* seql = (_Float16*)(ws + off); off += (size_t)CHUNK * 2048;
  float* gi      = ws + off; off += (size_t)16384 * 768;
  float* ys1     = ws + off; off += (size_t)16384 * 256;
  _Float16* ysh  = (_Float16*)(ws + off); off += (size_t)16384 * 128;
  _Float16* ysl  = (_Float16*)(ws + off); off += (size_t)16384 * 128;
  uint4* wp0     = (uint4*)(ws + off); off += 98304;
  uint4* wp1     = (uint4*)(ws + off); off += 98304;
  _Float16* bh0  = (_Float16*)(ws + off); off += (size_t)768 * 2048;
  _Float16* bl0  = (_Float16*)(ws + off); off += (size_t)768 * 2048;
  _Float16* bh1  = (_Float16*)(ws + off); off += (size_t)768 * 128;
  _Float16* bl1  = (_Float16*)(ws + off); off += (size_t)768 * 128;

  k_pack_frag<<<96, 256, 0, stream>>>(Whh0, wp0);
  k_pack_frag<<<96, 256, 0, stream>>>(Whh1, wp1);
  k_split16<<<(3145728 + 255) / 256, 256, 0, stream>>>(Wih0, bh0, bl0, 3145728);
  k_split16<<<(196608 + 255) / 256, 256, 0, stream>>>(Wih1, bh1, bl1, 196608);

  const int nChunks = 16384 / CHUNK;
  for (int ci = 0; ci < nChunks; ++ci) {
    const int base = ci * CHUNK;
    k_gcn<<<CHUNK, 256, 0, stream>>>(x, adj, W0, b0, W1, b1, bng, bnbb, bnm, bnv,
                                     seqh, seql, base);
    const int mB = CHUNK / 128;
    k_gemm_mfma<<<mB * 6, 256, 0, stream>>>(seqh, seql, bh0, bl0, bih0,
                                            gi + (size_t)base * 768, 4096, mB);
  }
  // GRU0: emits only f16 hi/lo (consumed by gi1 GEMM)
  k_gru<false, true><<<32, 512, 0, stream>>>(gi, wp0, bhh0, nullptr, ysh, ysl);
  k_gemm_mfma<<<128 * 6, 256, 0, stream>>>(ysh, ysl, bh1, bl1, bih1, gi, 256, 128);
  // GRU1: emits only fp32 (consumed by head)
  k_gru<true, false><<<32, 512, 0, stream>>>(gi, wp1, bhh1, ys1, nullptr, nullptr);
  k_head<<<32, 128, 0, stream>>>(ys1, fc1w, fc1b, fc2w, fc2b, out);
}

// Round 9
// 3005.446 us; speedup vs baseline: 1.0159x; 1.0159x over previous
//
#include <hip/hip_runtime.h>
#include <hip/hip_bf16.h>

// TSGCN: GCN(2 layers, fused) -> GRU(4096->256) -> GRU(256->256) -> FC head
// B=32 S=512 N=64 F=16 G=64 H=256.
// R9: (1) GRU step barrier -> raw s_barrier + lgkmcnt(0) only (syncthreads'
// implicit vmcnt(0) was draining ys stores every step, ~1000 cy); (2) GRU1
// writes ys only at step 511; (3) GEMM: revert R7 block mapping (R8 swizzle
// thrashed B in L2) + term-outer MFMA order (break same-acc dependent runs).

#define EPS_BN 1e-5f

typedef float f32x4 __attribute__((ext_vector_type(4)));
typedef unsigned u32x4v __attribute__((ext_vector_type(4)));

// LDS-only barrier: stores/loads in flight are NOT drained (unlike __syncthreads)
#define GRU_BARRIER() do {                       \
    asm volatile("" ::: "memory");               \
    asm volatile("s_waitcnt lgkmcnt(0)");        \
    __builtin_amdgcn_s_barrier();                \
    asm volatile("" ::: "memory");               \
  } while (0)

// ---------------------------------------------------- fp32 -> f16 hi/lo split
__global__ void k_split16(const float* __restrict__ src,
                          _Float16* __restrict__ hi, _Float16* __restrict__ lo,
                          int n) {
  int i = blockIdx.x * 256 + threadIdx.x;
  if (i >= n) return;
  float v = src[i];
  _Float16 h = (_Float16)v;
  hi[i] = h;
  lo[i] = (_Float16)(v - (float)h);
}

// ---------------------------------------------- pack Whh into MFMA B-fragments
// Tile map: fragment (w, nt, ks) covers n-tile (w + 8*nt):
//   n = 16*w + 128*nt + (l&15), k = 32*ks + 8*(l>>4) + j.
__global__ void k_pack_frag(const float* __restrict__ whh, uint4* __restrict__ wp) {
  int tid = blockIdx.x * 256 + threadIdx.x;
  if (tid >= 24576) return;
  int l = tid & 63;
  int rest = tid >> 6;
  int ks = rest & 7; rest >>= 3;
  int nt = rest % 6;
  int w  = rest / 6;
  int n  = 16 * w + 128 * nt + (l & 15);
  int kb = ks * 32 + (l >> 4) * 8;
  const float* src = whh + (size_t)n * 256 + kb;
  unsigned dw[4];
#pragma unroll
  for (int d = 0; d < 4; ++d) {
    unsigned short lo = __builtin_bit_cast(unsigned short, (_Float16)src[2 * d]);
    unsigned short hi = __builtin_bit_cast(unsigned short, (_Float16)src[2 * d + 1]);
    dw[d] = (unsigned)lo | ((unsigned)hi << 16);
  }
  wp[tid] = make_uint4(dw[0], dw[1], dw[2], dw[3]);
}

// ------------------------------------------------------------- fused GCN
__global__ __launch_bounds__(256) void k_gcn(
    const float* __restrict__ x, const float* __restrict__ adj,
    const float* __restrict__ W0, const float* __restrict__ b0,
    const float* __restrict__ W1, const float* __restrict__ b1,
    const float* __restrict__ bn_g, const float* __restrict__ bn_b,
    const float* __restrict__ bn_m, const float* __restrict__ bn_v,
    _Float16* __restrict__ seqh, _Float16* __restrict__ seql, int base)
{
  __shared__ float As[4096];
  __shared__ float Xs[1024];
  __shared__ float Hs[4096];
  __shared__ float Qs[4096];
  __shared__ float bnm_s[64], bns_s[64], bnb_s[64];

  const int t = threadIdx.x;
  const int lane = t & 63;
  const int w = t >> 6;
  const int m = base + blockIdx.x;

  {
    const float4* a4 = (const float4*)adj;
    float4* s4 = (float4*)As;
#pragma unroll
    for (int p = 0; p < 4; ++p) s4[t + 256 * p] = a4[t + 256 * p];
    ((float4*)Xs)[t] = ((const float4*)(x + (size_t)m * 1024))[t];
  }
  if (t < 64) {
    bns_s[t] = rsqrtf(bn_v[t] + EPS_BN) * bn_g[t];
    bnm_s[t] = bn_m[t];
    bnb_s[t] = bn_b[t];
  }
  float w0r[16];
#pragma unroll
  for (int f = 0; f < 16; ++f) w0r[f] = W0[f * 64 + lane];
  const float b0v = b0[lane], b1v = b1[lane];
  __syncthreads();

  float p[64];
#pragma unroll
  for (int v = 0; v < 64; ++v) {
    float acc = 0.f;
#pragma unroll
    for (int f = 0; f < 16; ++f) acc += Xs[v * 16 + f] * w0r[f];
    p[v] = acc;
  }
#pragma unroll
  for (int uu = 0; uu < 16; ++uu) {
    int u = w * 16 + uu;
    float acc = 0.f;
#pragma unroll
    for (int v = 0; v < 64; ++v) acc += As[u * 64 + v] * p[v];
    float h1 = fmaxf(acc + b0v, 0.f);
    h1 = (h1 - bnm_s[u]) * bns_s[u] + bnb_s[u];
    Hs[u * 64 + lane] = h1;
  }
  __syncthreads();
  float w1r[64];
#pragma unroll
  for (int f = 0; f < 64; ++f) w1r[f] = W1[f * 64 + lane];
#pragma unroll
  for (int vv = 0; vv < 16; ++vv) {
    int v = w * 16 + vv;
    float acc = 0.f;
#pragma unroll
    for (int f = 0; f < 64; ++f) acc += Hs[v * 64 + f] * w1r[f];
    Qs[v * 64 + lane] = acc;
  }
  __syncthreads();
  float q[64];
#pragma unroll
  for (int v = 0; v < 64; ++v) q[v] = Qs[v * 64 + lane];
  _Float16* oh = seqh + (size_t)blockIdx.x * 4096;
  _Float16* ol = seql + (size_t)blockIdx.x * 4096;
#pragma unroll
  for (int uu = 0; uu < 16; ++uu) {
    int u = w * 16 + uu;
    float acc = 0.f;
#pragma unroll
    for (int v = 0; v < 64; ++v) acc += As[u * 64 + v] * q[v];
    float val = fmaxf(acc + b1v, 0.f);
    _Float16 hv = (_Float16)val;
    oh[u * 64 + lane] = hv;
    ol[u * 64 + lane] = (_Float16)(val - (float)hv);
  }
}

// ----------------------------------------------- MFMA GEMM  C = A@B^T + bias
// 3-term hi/lo split, LDS-free. R7 block mapping (A-sharers co-XCD since
// mBlocks%8==0; B nb-slice L2-resident). Term-outer MFMA order: same-acc
// reuse distance 16 (no dependent back-to-back accumulate stalls).
#define MFMA_VV(c, a, b) asm volatile("v_mfma_f32_16x16x32_f16 %0, %1, %2, %0" \
                                      : "+v"(c) : "v"(a), "v"(b))

__global__ __launch_bounds__(256, 2) void k_gemm_mfma(
    const _Float16* __restrict__ Ah, const _Float16* __restrict__ Al,
    const _Float16* __restrict__ Bh, const _Float16* __restrict__ Bl,
    const float* __restrict__ bias,
    float* __restrict__ C,
    int K, int mBlocks)
{
  const int bid = blockIdx.x;
  const int mb = bid % mBlocks;
  const int nb = bid / mBlocks;
  const int t = threadIdx.x;
  const int w = t >> 6, l = t & 63;
  const int m0 = mb * 128 + (w >> 1) * 64;
  const int n0 = nb * 128 + (w & 1) * 64;
  const int row = l & 15;
  const int kk = (l >> 4) * 8;

  const _Float16* ah = Ah + (size_t)(m0 + row) * K + kk;
  const _Float16* al = Al + (size_t)(m0 + row) * K + kk;
  const _Float16* bh = Bh + (size_t)(n0 + row) * K + kk;
  const _Float16* bl = Bl + (size_t)(n0 + row) * K + kk;

  f32x4 acc[4][4] = {};

  for (int kt = 0; kt < K; kt += 32) {
    u32x4v af_h[4], af_l[4], bf_h[4], bf_l[4];
#pragma unroll
    for (int i = 0; i < 4; ++i) {
      const size_t o = (size_t)(16 * i) * K + kt;
      af_h[i] = *(const u32x4v*)(ah + o);
      af_l[i] = *(const u32x4v*)(al + o);
      bf_h[i] = *(const u32x4v*)(bh + o);
      bf_l[i] = *(const u32x4v*)(bl + o);
    }
    // term-outer: per-acc order is still hh -> lh -> hl (bitwise identical),
    // but consecutive MFMAs always target different accumulators.
#pragma unroll
    for (int mi = 0; mi < 4; ++mi)
#pragma unroll
      for (int ni = 0; ni < 4; ++ni)
        MFMA_VV(acc[mi][ni], af_h[mi], bf_h[ni]);
#pragma unroll
    for (int mi = 0; mi < 4; ++mi)
#pragma unroll
      for (int ni = 0; ni < 4; ++ni)
        MFMA_VV(acc[mi][ni], af_l[mi], bf_h[ni]);
#pragma unroll
    for (int mi = 0; mi < 4; ++mi)
#pragma unroll
      for (int ni = 0; ni < 4; ++ni)
        MFMA_VV(acc[mi][ni], af_h[mi], bf_l[ni]);
  }

  asm volatile("s_nop 7\n\ts_nop 7");

  const int r4 = (l >> 4) * 4;
#pragma unroll
  for (int ni = 0; ni < 4; ++ni) {
    const float bv = bias[n0 + 16 * ni + row];
#pragma unroll
    for (int mi = 0; mi < 4; ++mi) {
      float* cp = C + (size_t)(m0 + 16 * mi + r4) * 768 + n0 + 16 * ni + row;
      cp[0]    = acc[mi][ni].x + bv;
      cp[768]  = acc[mi][ni].y + bv;
      cp[1536] = acc[mi][ni].z + bv;
      cp[2304] = acc[mi][ni].w + bv;
    }
  }
}

// ------------------------------------------------------------------ GRU layer
// All 48 B-fragments AGPR-pinned; wave-local gates; ONE LDS-only barrier per
// step (global stores stay in flight across steps).
#define MFMA_A(c, a, b) asm volatile("v_mfma_f32_16x16x32_f16 %0, %1, %2, %0" \
                                     : "+v"(c) : "v"(a), "a"(b))

template <bool WF16, bool LASTONLY>
__global__ __launch_bounds__(512, 2) void k_gru(
    const float* __restrict__ gi,        // [32*512][768]
    const uint4* __restrict__ wp,        // packed B-fragments (k_pack_frag)
    const float* __restrict__ bhh,       // [768]
    float* __restrict__ ys,              // [32*512][256] fp32 (step 511 only, if LASTONLY)
    _Float16* __restrict__ ysh,          // [32*512][256] f16 hi (if WF16)
    _Float16* __restrict__ ysl)          // [32*512][256] f16 lo (if WF16)
{
  const int b = blockIdx.x;
  const int t = threadIdx.x;
  const int w = t >> 6;        // wave 0..7
  const int l = t & 63;

  __shared__ __align__(16) _Float16 h2[2][256];  // double-buffered f16 h

  const u32x4v* wp4 = (const u32x4v*)wp;
  const int wbase = w * 6;

  // ---- ALL B-fragments (8 k-slices x 6 tiles) -> named vars pinned via "a"
#define LBK(nt, ks) const u32x4v b##nt##_##ks = wp4[(((wbase + nt) * 8 + ks) << 6) + l];
#define LBNT(nt) LBK(nt,0) LBK(nt,1) LBK(nt,2) LBK(nt,3) \
                 LBK(nt,4) LBK(nt,5) LBK(nt,6) LBK(nt,7)
  LBNT(0) LBNT(1) LBNT(2) LBNT(3) LBNT(4) LBNT(5)
#undef LBNT
#undef LBK

  // lane's output index: l<32 active, j = 16w + (l&15) + 128*(l>>4)
  const int half = (l >> 4) & 1;
  const int j = 16 * w + (l & 15) + 128 * half;
  const bool act = (l < 32);
  float br = 0.f, bz = 0.f, bn = 0.f;
  float hold = 0.f;
  if (act) { br = bhh[j]; bz = bhh[256 + j]; bn = bhh[512 + j]; }
  if (t < 256) { h2[0][t] = (_Float16)0.f; h2[1][t] = (_Float16)0.f; }
  __syncthreads();

  const float* gib = gi + (size_t)b * 512 * 768;
  const char* h2c = (const char*)h2;
  const int g16 = (l >> 4) * 16;
  int cur = 0;

#pragma unroll 1
  for (int step = 0; step < 512; ++step) {
    // gi loads for this step; ~1800 cy of MFMA below hides their latency
    float ir = 0.f, iz = 0.f, inn = 0.f;
    if (act) {
      const float* g = gib + (size_t)step * 768;
      ir = g[j]; iz = g[256 + j]; inn = g[512 + j];
    }

    f32x4 c0 = {0.f,0.f,0.f,0.f}, c1 = c0, c2 = c0, c3 = c0, c4 = c0, c5 = c0;

#define DOT_KS(ks) { \
    const u32x4v a = *(const u32x4v*)(h2c + cur * 512 + (ks) * 64 + g16); \
    MFMA_A(c0, a, b0_##ks); MFMA_A(c1, a, b1_##ks); MFMA_A(c2, a, b2_##ks); \
    MFMA_A(c3, a, b3_##ks); MFMA_A(c4, a, b4_##ks); MFMA_A(c5, a, b5_##ks); }
    DOT_KS(0) DOT_KS(1) DOT_KS(2) DOT_KS(3)
    DOT_KS(4) DOT_KS(5) DOT_KS(6) DOT_KS(7)
#undef DOT_KS
    // MFMA-write -> VALU-read hazard guard
    asm volatile("s_nop 7\n\ts_nop 7");

    // wave-local gate math: half 0 uses c0/c2/c4, half 1 uses c1/c3/c5
    if (act) {
      const float cr = half ? c1.x : c0.x;
      const float cz = half ? c3.x : c2.x;
      const float cn = half ? c5.x : c4.x;
      const float r = __builtin_amdgcn_rcpf(1.f + __expf(-(ir + cr + br)));
      const float z = __builtin_amdgcn_rcpf(1.f + __expf(-(iz + cz + bz)));
      const float e2 = __expf(2.f * (inn + r * (cn + bn)));
      const float n = 1.f - 2.f * __builtin_amdgcn_rcpf(e2 + 1.f);
      hold = (1.f - z) * n + z * hold;
      h2[cur ^ 1][j] = (_Float16)hold;
      const size_t rowi = (size_t)b * 512 + step;
      if (WF16) {
        const _Float16 hh = (_Float16)hold;
        ysh[rowi * 256 + j] = hh;
        ysl[rowi * 256 + j] = (_Float16)(hold - (float)hh);
      }
      if (LASTONLY) {
        if (step == 511) ys[rowi * 256 + j] = hold;
      }
    }
    // LDS-only barrier: h2 writes visible, global stores NOT drained
    GRU_BARRIER();
    cur ^= 1;
  }
}

// ------------------------------------------------------------------ FC head
__global__ __launch_bounds__(128) void k_head(
    const float* __restrict__ ys1,
    const float* __restrict__ fc1w, const float* __restrict__ fc1b,
    const float* __restrict__ fc2w, const float* __restrict__ fc2b,
    float* __restrict__ out)
{
  __shared__ float last[256];
  __shared__ float o1[128];
  const int b = blockIdx.x, t = threadIdx.x;
  const float* src = ys1 + (size_t)(b * 512 + 511) * 256;
  last[t] = src[t];
  last[128 + t] = src[128 + t];
  __syncthreads();
  float acc = fc1b[t];
#pragma unroll 8
  for (int k = 0; k < 256; ++k) acc += last[k] * fc1w[k * 128 + t];
  o1[t] = fmaxf(acc, 0.f);
  __syncthreads();
  if (t < 64) {
    float acc2 = fc2b[t];
#pragma unroll 8
    for (int i = 0; i < 128; ++i) acc2 += o1[i] * fc2w[i * 64 + t];
    out[b * 64 + t] = acc2;
  }
}

// ------------------------------------------------------------------ launcher
extern "C" void kernel_launch(void* const* d_in, const int* in_sizes, int n_in,
                              void* d_out, int out_size, void* d_ws, size_t ws_size,
                              hipStream_t stream)
{
  const float* x    = (const float*)d_in[0];
  const float* adj  = (const float*)d_in[1];
  const float* W0   = (const float*)d_in[2];
  const float* b0   = (const float*)d_in[3];
  const float* W1   = (const float*)d_in[4];
  const float* b1   = (const float*)d_in[5];
  const float* bng  = (const float*)d_in[6];
  const float* bnbb = (const float*)d_in[7];
  const float* bnm  = (const float*)d_in[8];
  const float* bnv  = (const float*)d_in[9];
  const float* Wih0 = (const float*)d_in[10];
  const float* Whh0 = (const float*)d_in[11];
  const float* bih0 = (const float*)d_in[12];
  const float* bhh0 = (const float*)d_in[13];
  const float* Wih1 = (const float*)d_in[14];
  const float* Whh1 = (const float*)d_in[15];
  const float* bih1 = (const float*)d_in[16];
  const float* bhh1 = (const float*)d_in[17];
  const float* fc1w = (const float*)d_in[18];
  const float* fc1b = (const float*)d_in[19];
  const float* fc2w = (const float*)d_in[20];
  const float* fc2b = (const float*)d_in[21];
  float* out = (float*)d_out;

  float* ws = (float*)d_ws;
  const size_t fixed = (size_t)16384 * 768 + (size_t)16384 * 256
                     + 2 * ((size_t)16384 * 128)
                     + 2 * 98304
                     + 2 * ((size_t)768 * 4096 / 2)
                     + 2 * ((size_t)768 * 256 / 2);
  int CHUNK = 16384;
  while (CHUNK > 128 && ((size_t)CHUNK * 4096 + fixed) * 4 > ws_size) CHUNK >>= 1;

  size_t off = 0;
  _Float16* seqh = (_Float16*)(ws + off); off += (size_t)CHUNK * 2048;
  _Float16* seql = (_Float16*)(ws + off); off += (size_t)CHUNK * 2048;
  float* gi      = ws + off; off += (size_t)16384 * 768;
  float* ys1     = ws + off; off += (size_t)16384 * 256;
  _Float16* ysh  = (_Float16*)(ws + off); off += (size_t)16384 * 128;
  _Float16* ysl  = (_Float16*)(ws + off); off += (size_t)16384 * 128;
  uint4* wp0     = (uint4*)(ws + off); off += 98304;
  uint4* wp1     = (uint4*)(ws + off); off += 98304;
  _Float16* bh0  = (_Float16*)(ws + off); off += (size_t)768 * 2048;
  _Float16* bl0  = (_Float16*)(ws + off); off += (size_t)768 * 2048;
  _Float16* bh1  = (_Float16*)(ws + off); off += (size_t)768 * 128;
  _Float16* bl1  = (_Float16*)(ws + off); off += (size_t)768 * 128;

  k_pack_frag<<<96, 256, 0, stream>>>(Whh0, wp0);
  k_pack_frag<<<96, 256, 0, stream>>>(Whh1, wp1);
  k_split16<<<(3145728 + 255) / 256, 256, 0, stream>>>(Wih0, bh0, bl0, 3145728);
  k_split16<<<(196608 + 255) / 256, 256, 0, stream>>>(Wih1, bh1, bl1, 196608);

  const int nChunks = 16384 / CHUNK;
  for (int ci = 0; ci < nChunks; ++ci) {
    const int base = ci * CHUNK;
    k_gcn<<<CHUNK, 256, 0, stream>>>(x, adj, W0, b0, W1, b1, bng, bnbb, bnm, bnv,
                                     seqh, seql, base);
    const int mB = CHUNK / 128;
    k_gemm_mfma<<<mB * 6, 256, 0, stream>>>(seqh, seql, bh0, bl0, bih0,
                                            gi + (size_t)base * 768, 4096, mB);
  }
  // GRU0: emits f16 hi/lo every step (consumed by gi1 GEMM)
  k_gru<true, false><<<32, 512, 0, stream>>>(gi, wp0, bhh0, nullptr, ysh, ysl);
  k_gemm_mfma<<<128 * 6, 256, 0, stream>>>(ysh, ysl, bh1, bl1, bih1, gi, 256, 128);
  // GRU1: emits fp32 at step 511 only (consumed by head)
  k_gru<false, true><<<32, 512, 0, stream>>>(gi, wp1, bhh1, ys1, nullptr, nullptr);
  k_head<<<32, 128, 0, stream>>>(ys1, fc1w, fc1b, fc2w, fc2b, out);
}